// Round 1
// baseline (149.842 us; speedup 1.0000x reference)
//
#include <hip/hip_runtime.h>
#include <math.h>

#define N_FILT 64
#define IMG_DIM 256
#define IMG_SZ (256*256)
#define HDIM 1024
#define NBATCH 512

// ws layout:
//   int meta[48]: [0..7]=aloY  [8..15]=ahiY  (8 n-groups of 8, stage 1)
//                 [16..31]=bloX [32..47]=bhiX (16 m-groups of 4, stage 2)
//   byte 256           : fyg [8][256][8]  float (gamma/SY folded)   64 KiB
//   byte 256+65536     : fxg [16][256][4] float (1/SX folded)       64 KiB

__global__ __launch_bounds__(256) void k_prep(
    const float* __restrict__ h, const float* __restrict__ Ww,
    const float* __restrict__ Wb, int* __restrict__ meta,
    float* __restrict__ fyg, float* __restrict__ fxg)
{
  __shared__ float red[256];
  __shared__ float par[8];
  __shared__ float F[N_FILT*IMG_DIM];
  __shared__ int s_lo[64], s_hi[64], s_glo[16], s_ghi[16];
  const int t = threadIdx.x;

  // ---- params[j] = h[0] . W_read_w[j] + W_read_b[j] ----
  #pragma unroll
  for (int j=0;j<5;++j){
    float s=0.f;
    for (int k=t;k<HDIM;k+=256) s = fmaf(h[k], Ww[j*HDIM+k], s);
    red[t]=s; __syncthreads();
    for (int o=128;o>0;o>>=1){ if (t<o) red[t]+=red[t+o]; __syncthreads(); }
    if (t==0) par[j]=red[0]+Wb[j];
    __syncthreads();
  }
  const float var   = expf(par[2]+1e-8f);
  const float dt    = expf(par[3]);
  const float gamma = expf(par[4]);
  const float gX = 0.5f*257.f*(par[0]+1.f);
  const float gY = 0.5f*257.f*(par[1]+1.f);
  const float d  = dt*(255.f/63.f);
  const float sub= -32.5f*d;
  const float inv2v = 1.f/(2.f*var);
  const float w88v  = 88.f*var;   // band cutoff: e(a)/e(peak) >= exp(-44)

  // ========== F_Y (stage-1 row weights, mu from gY), n-groups of 8 ==========
  if (t<64){
    float mu = gY + sub + d*(float)t;
    float astar = fminf(255.f, fmaxf(0.f, rintf(mu)));   // clamped peak
    float t0 = (astar-mu)*(astar-mu);
    float r  = sqrtf(t0 + w88v);
    int lo = (int)ceilf(mu-r); int hi = (int)floorf(mu+r)+1;
    lo = lo<0?0:lo; hi = hi>256?256:hi; if (hi<lo) hi=lo;
    s_lo[t]=lo; s_hi[t]=hi;
  }
  __syncthreads();
  if (t<8){
    int lo=256, hi=0;
    #pragma unroll
    for (int k2=0;k2<8;++k2){ lo=min(lo,s_lo[t*8+k2]); hi=max(hi,s_hi[t*8+k2]); }
    if (hi<lo){lo=0;hi=0;}
    meta[t]=lo; meta[8+t]=hi; s_glo[t]=lo; s_ghi[t]=hi;
  }
  float sum=0.f;
  for (int idx=t; idx<N_FILT*IMG_DIM; idx+=256){
    int n=idx>>8, a=idx&255;
    float mu = gY + sub + d*(float)n;
    float dx = (float)a - mu;
    float e = expf(-dx*dx*inv2v);
    F[idx]=e; sum+=e;
  }
  red[t]=sum; __syncthreads();
  for (int o=128;o>0;o>>=1){ if (t<o) red[t]+=red[t+o]; __syncthreads(); }
  const float scY = gamma/red[0];          // global normalization + gamma fold
  __syncthreads();
  for (int idx=t; idx<N_FILT*IMG_DIM; idx+=256){
    int n=idx>>8, a=idx&255, g=n>>3;
    int lo=s_glo[g], hi=s_ghi[g];
    if (a>=lo && a<hi) fyg[(size_t)(((g<<8)+(a-lo))<<3) + (n&7)] = F[idx]*scY;
  }
  __syncthreads();

  // ========== F_X (stage-2 col weights, mu from gX), m-groups of 4 ==========
  if (t<64){
    float mu = gX + sub + d*(float)t;
    float astar = fminf(255.f, fmaxf(0.f, rintf(mu)));
    float t0 = (astar-mu)*(astar-mu);
    float r  = sqrtf(t0 + w88v);
    int lo = (int)ceilf(mu-r); int hi = (int)floorf(mu+r)+1;
    lo = lo<0?0:lo; hi = hi>256?256:hi; if (hi<lo) hi=lo;
    s_lo[t]=lo; s_hi[t]=hi;
  }
  __syncthreads();
  if (t<16){
    int lo=256, hi=0;
    #pragma unroll
    for (int k2=0;k2<4;++k2){ lo=min(lo,s_lo[t*4+k2]); hi=max(hi,s_hi[t*4+k2]); }
    if (hi<lo){lo=0;hi=0;}
    meta[16+t]=lo; meta[32+t]=hi; s_glo[t]=lo; s_ghi[t]=hi;
  }
  float sum2=0.f;
  for (int idx=t; idx<N_FILT*IMG_DIM; idx+=256){
    int m=idx>>8, b=idx&255;
    float mu = gX + sub + d*(float)m;
    float dx=(float)b-mu;
    float e=expf(-dx*dx*inv2v);
    F[idx]=e; sum2+=e;
  }
  red[t]=sum2; __syncthreads();
  for (int o=128;o>0;o>>=1){ if (t<o) red[t]+=red[t+o]; __syncthreads(); }
  const float scX = 1.f/red[0];
  __syncthreads();
  for (int idx=t; idx<N_FILT*IMG_DIM; idx+=256){
    int m=idx>>8, b=idx&255, q=m>>2;
    int lo=s_glo[q], hi=s_ghi[q];
    if (b>=lo && b<hi) fxg[(size_t)(((q<<8)+(b-lo))<<2) + (m&3)] = F[idx]*scX;
  }
}

// One block per image (1024 blocks). 4 waves; wave w owns n in [16w,16w+16)
// for stage 1 and m in [16w,16w+16) for stage 2.
__global__ __launch_bounds__(256) void k_main(
    const float* __restrict__ x, const float* __restrict__ xh,
    const int* __restrict__ meta, const float* __restrict__ fyg,
    const float* __restrict__ fxg, float* __restrict__ out)
{
  __shared__ float Tt[256*65];   // T^T[b][n], stride 65 (==1 mod 32: conflict-free reads)
  const int i    = blockIdx.x;
  const int tid  = threadIdx.x;
  const int w    = __builtin_amdgcn_readfirstlane(tid>>6);
  const int lane = tid & 63;
  const float* __restrict__ src = (i<NBATCH) ? (x  + (size_t)i*IMG_SZ)
                                             : (xh + (size_t)(i-NBATCH)*IMG_SZ);
  float* __restrict__ dst = (i<NBATCH) ? (out + (size_t)i*8192)
                                       : (out + (size_t)(i-NBATCH)*8192 + 4096);

  // ---- stage 1: T[n][b] = sum_a FY[n][a]*src[a][b]; lane owns cols 4L..4L+3 ----
  #pragma unroll
  for (int gs=0; gs<2; ++gs){
    const int g  = w*2 + gs;
    const int a0 = __builtin_amdgcn_readfirstlane(meta[g]);
    const int a1 = __builtin_amdgcn_readfirstlane(meta[8+g]);
    float acc[8][4];
    #pragma unroll
    for (int k2=0;k2<8;++k2){acc[k2][0]=0.f;acc[k2][1]=0.f;acc[k2][2]=0.f;acc[k2][3]=0.f;}
    const float* rp = src + (size_t)a0*256 + 4*lane;
    const float* wp = fyg + ((size_t)g<<11);   // [256][8] rows from a0
    #pragma unroll 2
    for (int a=a0; a<a1; ++a){
      const float4 row = *(const float4* __restrict__)rp;
      #pragma unroll
      for (int k2=0;k2<8;++k2){
        const float wv = wp[k2];               // wave-uniform -> scalar load
        acc[k2][0]=fmaf(wv,row.x,acc[k2][0]);
        acc[k2][1]=fmaf(wv,row.y,acc[k2][1]);
        acc[k2][2]=fmaf(wv,row.z,acc[k2][2]);
        acc[k2][3]=fmaf(wv,row.w,acc[k2][3]);
      }
      rp += 256; wp += 8;
    }
    #pragma unroll
    for (int k2=0;k2<8;++k2){
      const int n = g*8 + k2;
      #pragma unroll
      for (int j=0;j<4;++j) Tt[(4*lane+j)*65 + n] = acc[k2][j];
    }
  }
  __syncthreads();

  // ---- stage 2: out[n][m] = sum_b T[n][b]*FX[m][b]; lanes = n ----
  float o4[4][4];
  #pragma unroll
  for (int qs=0; qs<4; ++qs){
    const int q  = w*4 + qs;
    const int b0 = __builtin_amdgcn_readfirstlane(meta[16+q]);
    const int b1 = __builtin_amdgcn_readfirstlane(meta[32+q]);
    float c0=0.f,c1=0.f,c2=0.f,c3=0.f;
    const float* wq = fxg + ((size_t)q<<10);   // [256][4] rows from b0
    #pragma unroll 2
    for (int b=b0; b<b1; ++b){
      const float tv = Tt[b*65 + lane];
      c0 = fmaf(wq[0], tv, c0);
      c1 = fmaf(wq[1], tv, c1);
      c2 = fmaf(wq[2], tv, c2);
      c3 = fmaf(wq[3], tv, c3);
      wq += 4;
    }
    o4[qs][0]=c0; o4[qs][1]=c1; o4[qs][2]=c2; o4[qs][3]=c3;
  }
  __syncthreads();   // all stage-2 reads of Tt done before overwrite

  // ---- transpose via LDS (stride 68 keeps float4 16B-aligned), coalesced store ----
  #pragma unroll
  for (int qs=0; qs<4; ++qs){
    const int q = w*4+qs;
    #pragma unroll
    for (int k2=0;k2<4;++k2) Tt[lane*68 + q*4 + k2] = o4[qs][k2];
  }
  __syncthreads();
  #pragma unroll
  for (int rr=0; rr<4; ++rr){
    const int f = rr*1024 + tid*4;
    const int n = f>>6, m = f&63;
    const float4 v = *(const float4*)&Tt[n*68+m];
    *(float4*)(dst+f) = v;
  }
}

extern "C" void kernel_launch(void* const* d_in, const int* in_sizes, int n_in,
                              void* d_out, int out_size, void* d_ws, size_t ws_size,
                              hipStream_t stream)
{
  const float* x  = (const float*)d_in[0];
  const float* xh = (const float*)d_in[1];
  const float* h  = (const float*)d_in[2];   // only row 0 is used
  const float* Ww = (const float*)d_in[3];
  const float* Wb = (const float*)d_in[4];
  float* out = (float*)d_out;

  int*   meta = (int*)d_ws;
  float* fyg  = (float*)((char*)d_ws + 256);
  float* fxg  = (float*)((char*)d_ws + 256 + 65536);

  k_prep<<<1, 256, 0, stream>>>(h, Ww, Wb, meta, fyg, fxg);
  k_main<<<2*NBATCH, 256, 0, stream>>>(x, xh, meta, fyg, fxg, out);
}

// Round 2
// 112.250 us; speedup vs baseline: 1.3349x; 1.3349x over previous
//
#include <hip/hip_runtime.h>
#include <math.h>

#define N_FILT 64
#define IMG_DIM 256
#define IMG_SZ (256*256)
#define HDIM 1024
#define NBATCH 512

// ws layout:
//   int meta[48]: [0..7]=aloY  [8..15]=ahiY  (8 n-groups of 8, stage 1)
//                 [16..31]=lo4X (granule-aligned) [32..47]=hiX (16 m-groups of 4)
//   byte 256           : fyg [8][256][8]  float (gamma/SY folded)   64 KiB
//   byte 256+65536     : fxg [16][256][4] float (1/SX folded, packed from lo4,
//                        zero-filled so granule-aligned reads are safe)  64 KiB

__global__ __launch_bounds__(256) void k_prep(
    const float* __restrict__ h, const float* __restrict__ Ww,
    const float* __restrict__ Wb, int* __restrict__ meta,
    float* __restrict__ fyg, float* __restrict__ fxg)
{
  __shared__ float red[256];
  __shared__ float par[8];
  __shared__ float F[N_FILT*IMG_DIM];
  __shared__ int s_lo[64], s_hi[64], s_glo[16], s_ghi[16];
  const int t = threadIdx.x;

  // zero-fill fxg so granule-aligned stage-2 reads of band edges see 0
  {
    float4 z = make_float4(0.f,0.f,0.f,0.f);
    float4* p = (float4*)fxg;
    #pragma unroll
    for (int k=0;k<16;++k) p[t + 256*k] = z;
  }

  // ---- params[j] = h[0] . W_read_w[j] + W_read_b[j] ----
  #pragma unroll
  for (int j=0;j<5;++j){
    float s=0.f;
    for (int k=t;k<HDIM;k+=256) s = fmaf(h[k], Ww[j*HDIM+k], s);
    red[t]=s; __syncthreads();
    for (int o=128;o>0;o>>=1){ if (t<o) red[t]+=red[t+o]; __syncthreads(); }
    if (t==0) par[j]=red[0]+Wb[j];
    __syncthreads();
  }
  const float var   = expf(par[2]+1e-8f);
  const float dt    = expf(par[3]);
  const float gamma = expf(par[4]);
  const float gX = 0.5f*257.f*(par[0]+1.f);
  const float gY = 0.5f*257.f*(par[1]+1.f);
  const float d  = dt*(255.f/63.f);
  const float sub= -32.5f*d;
  const float inv2v = 1.f/(2.f*var);
  const float w88v  = 88.f*var;   // band cutoff: e(a)/e(peak) >= exp(-44)

  // ========== F_Y (stage-1 row weights, mu from gY), n-groups of 8 ==========
  if (t<64){
    float mu = gY + sub + d*(float)t;
    float astar = fminf(255.f, fmaxf(0.f, rintf(mu)));   // clamped peak
    float t0 = (astar-mu)*(astar-mu);
    float r  = sqrtf(t0 + w88v);
    int lo = (int)ceilf(mu-r); int hi = (int)floorf(mu+r)+1;
    lo = lo<0?0:lo; hi = hi>256?256:hi; if (hi<lo) hi=lo;
    s_lo[t]=lo; s_hi[t]=hi;
  }
  __syncthreads();
  if (t<8){
    int lo=256, hi=0;
    #pragma unroll
    for (int k2=0;k2<8;++k2){ lo=min(lo,s_lo[t*8+k2]); hi=max(hi,s_hi[t*8+k2]); }
    if (hi<lo){lo=0;hi=0;}
    meta[t]=lo; meta[8+t]=hi; s_glo[t]=lo; s_ghi[t]=hi;
  }
  float sum=0.f;
  for (int idx=t; idx<N_FILT*IMG_DIM; idx+=256){
    int n=idx>>8, a=idx&255;
    float mu = gY + sub + d*(float)n;
    float dx = (float)a - mu;
    float e = expf(-dx*dx*inv2v);
    F[idx]=e; sum+=e;
  }
  red[t]=sum; __syncthreads();
  for (int o=128;o>0;o>>=1){ if (t<o) red[t]+=red[t+o]; __syncthreads(); }
  const float scY = gamma/red[0];          // global normalization + gamma fold
  __syncthreads();
  for (int idx=t; idx<N_FILT*IMG_DIM; idx+=256){
    int n=idx>>8, a=idx&255, g=n>>3;
    int lo=s_glo[g], hi=s_ghi[g];
    if (a>=lo && a<hi) fyg[(size_t)(((g<<8)+(a-lo))<<3) + (n&7)] = F[idx]*scY;
  }
  __syncthreads();

  // ========== F_X (stage-2 col weights, mu from gX), m-groups of 4 ==========
  if (t<64){
    float mu = gX + sub + d*(float)t;
    float astar = fminf(255.f, fmaxf(0.f, rintf(mu)));
    float t0 = (astar-mu)*(astar-mu);
    float r  = sqrtf(t0 + w88v);
    int lo = (int)ceilf(mu-r); int hi = (int)floorf(mu+r)+1;
    lo = lo<0?0:lo; hi = hi>256?256:hi; if (hi<lo) hi=lo;
    s_lo[t]=lo; s_hi[t]=hi;
  }
  __syncthreads();
  if (t<16){
    int lo=256, hi=0;
    #pragma unroll
    for (int k2=0;k2<4;++k2){ lo=min(lo,s_lo[t*4+k2]); hi=max(hi,s_hi[t*4+k2]); }
    if (hi<lo){lo=0;hi=0;}
    int lo4 = lo & ~3;                      // granule-aligned pack origin
    meta[16+t]=lo4; meta[32+t]=hi; s_glo[t]=lo4; s_ghi[t]=hi;
  }
  float sum2=0.f;
  for (int idx=t; idx<N_FILT*IMG_DIM; idx+=256){
    int m=idx>>8, b=idx&255;
    float mu = gX + sub + d*(float)m;
    float dx=(float)b-mu;
    float e=expf(-dx*dx*inv2v);
    F[idx]=e; sum2+=e;
  }
  red[t]=sum2; __syncthreads();
  for (int o=128;o>0;o>>=1){ if (t<o) red[t]+=red[t+o]; __syncthreads(); }
  const float scX = 1.f/red[0];
  __syncthreads();
  for (int idx=t; idx<N_FILT*IMG_DIM; idx+=256){
    int m=idx>>8, b=idx&255, q=m>>2;
    int lo4=s_glo[q], hi=s_ghi[q];
    // true-band condition uses the row's real band; outside stays zero
    float mu = gX + sub + d*(float)m;
    float dx=(float)b-mu;
    if (b>=lo4 && b<hi && dx*dx*inv2v < 44.f + 1.f)
      fxg[(size_t)(((q<<8)+(b-lo4))<<2) + (m&3)] = F[idx]*scX;
  }
}

// 2048 blocks: 2 blocks per image, each owning 32 filters (n-half).
// 4 waves; wave w owns stage-1 group g = half*4+w (8 n's) and
// stage-2 m-range [16w,16w+16) split across half-waves.
__global__ __launch_bounds__(256, 4) void k_main(
    const float* __restrict__ x, const float* __restrict__ xh,
    const int* __restrict__ meta, const float* __restrict__ fyg,
    const float* __restrict__ fxg, float* __restrict__ out)
{
  __shared__ float Tt[32*256];   // swizzled T[n_local][b], exactly 32 KiB
  const int bid = blockIdx.x;
  const int lg  = ((bid&7)<<8) | (bid>>3);   // same-image pair -> same XCD
  const int img = lg>>1, half = lg&1;
  const int tid = threadIdx.x;
  const int w    = __builtin_amdgcn_readfirstlane(tid>>6);
  const int lane = tid & 63;
  const float* __restrict__ src = (img<NBATCH) ? (x  + (size_t)img*IMG_SZ)
                                               : (xh + (size_t)(img-NBATCH)*IMG_SZ);
  float* __restrict__ dst = ((img<NBATCH) ? (out + (size_t)img*8192)
                                          : (out + (size_t)(img-NBATCH)*8192 + 4096))
                            + half*2048;

  // ---- stage 1: T[n][b] = sum_a FY[n][a]*src[a][b]; lane owns cols 4L..4L+3 ----
  {
    const int g  = half*4 + w;
    const int a0 = __builtin_amdgcn_readfirstlane(meta[g]);
    const int a1 = __builtin_amdgcn_readfirstlane(meta[8+g]);
    float acc[8][4];
    #pragma unroll
    for (int k2=0;k2<8;++k2){acc[k2][0]=0.f;acc[k2][1]=0.f;acc[k2][2]=0.f;acc[k2][3]=0.f;}
    const float* rp = src + (size_t)a0*256 + 4*lane;
    const float* wp = fyg + ((size_t)g<<11);   // [256][8] rows from a0
    #pragma unroll 4
    for (int a=a0; a<a1; ++a){
      const float4 row = *(const float4* __restrict__)rp;
      #pragma unroll
      for (int k2=0;k2<8;++k2){
        const float wv = wp[k2];               // wave-uniform -> scalar load
        acc[k2][0]=fmaf(wv,row.x,acc[k2][0]);
        acc[k2][1]=fmaf(wv,row.y,acc[k2][1]);
        acc[k2][2]=fmaf(wv,row.z,acc[k2][2]);
        acc[k2][3]=fmaf(wv,row.w,acc[k2][3]);
      }
      rp += 256; wp += 8;
    }
    // b128 writes, granule-XOR swizzle: phys_granule = lane ^ (n&7) -> bank-uniform
    #pragma unroll
    for (int k2=0;k2<8;++k2){
      const int n = w*8 + k2;                  // wave-uniform row
      float4 v; v.x=acc[k2][0]; v.y=acc[k2][1]; v.z=acc[k2][2]; v.w=acc[k2][3];
      *(float4*)&Tt[(n<<8) + ((lane ^ (n&7))<<2)] = v;
    }
  }
  __syncthreads();

  // ---- stage 2: out[n][m] = sum_b T[n][b]*FX[m][b]; lane = n_local + 32*c ----
  const int nl = lane & 31;
  const int c  = lane >> 5;
  const int q0 = w*4 + c*2;                    // each half-wave: 2 m-groups of 4
  float o8[2][4];
  #pragma unroll
  for (int qs=0;qs<2;++qs){o8[qs][0]=0.f;o8[qs][1]=0.f;o8[qs][2]=0.f;o8[qs][3]=0.f;}
  #pragma unroll
  for (int qs=0; qs<2; ++qs){
    const int q   = q0 + qs;
    const int lo4 = meta[16+q];                // per-half -> vector load
    const int hi  = meta[32+q];
    const int ng  = (hi - lo4 + 3) >> 2;
    const int u0  = lo4 >> 2;
    const float* wq = fxg + ((size_t)q<<10);   // [256][4] rows packed from lo4
    #pragma unroll 2
    for (int it=0; it<ng; ++it){
      const int u = u0 + it;
      const float4 tv = *(const float4*)&Tt[(nl<<8) + ((u ^ (nl&7))<<2)];
      const float4 w0 = *(const float4*)(wq + it*16);      // b+0: m 0..3
      const float4 w1 = *(const float4*)(wq + it*16 + 4);  // b+1
      const float4 w2 = *(const float4*)(wq + it*16 + 8);  // b+2
      const float4 w3 = *(const float4*)(wq + it*16 + 12); // b+3
      o8[qs][0]=fmaf(tv.x,w0.x,fmaf(tv.y,w1.x,fmaf(tv.z,w2.x,fmaf(tv.w,w3.x,o8[qs][0]))));
      o8[qs][1]=fmaf(tv.x,w0.y,fmaf(tv.y,w1.y,fmaf(tv.z,w2.y,fmaf(tv.w,w3.y,o8[qs][1]))));
      o8[qs][2]=fmaf(tv.x,w0.z,fmaf(tv.y,w1.z,fmaf(tv.z,w2.z,fmaf(tv.w,w3.z,o8[qs][2]))));
      o8[qs][3]=fmaf(tv.x,w0.w,fmaf(tv.y,w1.w,fmaf(tv.z,w2.w,fmaf(tv.w,w3.w,o8[qs][3]))));
    }
  }
  __syncthreads();   // all stage-2 reads of Tt done before overwrite

  // ---- transpose via LDS (stride 68 keeps float4 16B-aligned), coalesced store ----
  #pragma unroll
  for (int qs=0; qs<2; ++qs){
    #pragma unroll
    for (int j=0;j<4;++j){
      const int m = (q0+qs)*4 + j;
      Tt[nl*68 + m] = o8[qs][j];
    }
  }
  __syncthreads();
  #pragma unroll
  for (int rr=0; rr<2; ++rr){
    const int f = rr*1024 + tid*4;
    const int n = f>>6, m = f&63;
    const float4 v = *(const float4*)&Tt[n*68+m];
    *(float4*)(dst+f) = v;
  }
}

extern "C" void kernel_launch(void* const* d_in, const int* in_sizes, int n_in,
                              void* d_out, int out_size, void* d_ws, size_t ws_size,
                              hipStream_t stream)
{
  const float* x  = (const float*)d_in[0];
  const float* xh = (const float*)d_in[1];
  const float* h  = (const float*)d_in[2];   // only row 0 is used
  const float* Ww = (const float*)d_in[3];
  const float* Wb = (const float*)d_in[4];
  float* out = (float*)d_out;

  int*   meta = (int*)d_ws;
  float* fyg  = (float*)((char*)d_ws + 256);
  float* fxg  = (float*)((char*)d_ws + 256 + 65536);

  k_prep<<<1, 256, 0, stream>>>(h, Ww, Wb, meta, fyg, fxg);
  k_main<<<4*NBATCH, 256, 0, stream>>>(x, xh, meta, fyg, fxg, out);
}

// Round 3
// 100.272 us; speedup vs baseline: 1.4944x; 1.1195x over previous
//
#include <hip/hip_runtime.h>
#include <math.h>

#define N_FILT 64
#define IMG_DIM 256
#define IMG_SZ (256*256)
#define HDIM 1024
#define NBATCH 512

// ws layout (131,328 B total — same footprint as round 2):
//   int meta[64]: [0..15]=aloY [16..31]=ahiY   (16 n-groups of 4, stage 1)
//                 [32..47]=lo4X (granule-aligned) [48..63]=hiX (16 m-groups of 4)
//   byte 256           : fyg [16][256][4] float (gamma/SY folded, zero-filled) 64 KiB
//   byte 256+65536     : fxg [16][256][4] float (1/SX folded, zero-filled)     64 KiB

__global__ __launch_bounds__(1024) void k_prep(
    const float* __restrict__ h, const float* __restrict__ Ww,
    const float* __restrict__ Wb, int* __restrict__ meta,
    float* __restrict__ fyg, float* __restrict__ fxg)
{
  __shared__ float red[1024];
  __shared__ float par[8];
  __shared__ float F[N_FILT*IMG_DIM];
  __shared__ int s_lo[64], s_hi[64], s_glo[16], s_ghi[16];
  const int t = threadIdx.x;

  // zero-fill both weight buffers (banded packs only overwrite in-band rows)
  {
    float4 z = make_float4(0.f,0.f,0.f,0.f);
    float4* p1 = (float4*)fyg; float4* p2 = (float4*)fxg;
    #pragma unroll
    for (int k=0;k<4;++k){ p1[t+1024*k]=z; p2[t+1024*k]=z; }
  }

  // ---- params[j] = h[0] . W_read_w[j] + W_read_b[j] ----
  #pragma unroll
  for (int j=0;j<5;++j){
    red[t] = h[t]*Ww[j*HDIM+t]; __syncthreads();
    for (int o=512;o>0;o>>=1){ if (t<o) red[t]+=red[t+o]; __syncthreads(); }
    if (t==0) par[j]=red[0]+Wb[j];
    __syncthreads();
  }
  const float var   = expf(par[2]+1e-8f);
  const float dt    = expf(par[3]);
  const float gamma = expf(par[4]);
  const float gX = 0.5f*257.f*(par[0]+1.f);
  const float gY = 0.5f*257.f*(par[1]+1.f);
  const float d  = dt*(255.f/63.f);
  const float sub= -32.5f*d;
  const float inv2v = 1.f/(2.f*var);
  const float w88v  = 88.f*var;   // band cutoff: e(a)/e(peak) >= exp(-44)

  // ========== F_Y (stage-1 row weights, mu from gY), 16 n-groups of 4 ==========
  if (t<64){
    float mu = gY + sub + d*(float)t;
    float astar = fminf(255.f, fmaxf(0.f, rintf(mu)));   // clamped peak
    float t0 = (astar-mu)*(astar-mu);
    float r  = sqrtf(t0 + w88v);
    int lo = (int)ceilf(mu-r); int hi = (int)floorf(mu+r)+1;
    lo = lo<0?0:lo; hi = hi>256?256:hi; if (hi<lo) hi=lo;
    s_lo[t]=lo; s_hi[t]=hi;
  }
  __syncthreads();
  if (t<16){
    int lo=256, hi=0;
    #pragma unroll
    for (int k2=0;k2<4;++k2){ lo=min(lo,s_lo[t*4+k2]); hi=max(hi,s_hi[t*4+k2]); }
    if (hi<lo){lo=0;hi=0;}
    meta[t]=lo; meta[16+t]=hi; s_glo[t]=lo; s_ghi[t]=hi;
  }
  {
    float sum=0.f;
    #pragma unroll
    for (int k=0;k<16;++k){
      int idx = t + 1024*k;
      int n=idx>>8, a=idx&255;
      float mu = gY + sub + d*(float)n;
      float dx = (float)a - mu;
      float e = expf(-dx*dx*inv2v);
      F[idx]=e; sum+=e;
    }
    red[t]=sum;
  }
  __syncthreads();
  for (int o=512;o>0;o>>=1){ if (t<o) red[t]+=red[t+o]; __syncthreads(); }
  const float scY = gamma/red[0];          // global normalization + gamma fold
  __syncthreads();
  #pragma unroll
  for (int k=0;k<16;++k){
    int idx = t + 1024*k;
    int n=idx>>8, a=idx&255, g=n>>2;
    int lo=s_glo[g], hi=s_ghi[g];
    if (a>=lo && a<hi) fyg[(size_t)((g<<10) + ((a-lo)<<2) + (n&3))] = F[idx]*scY;
  }
  __syncthreads();

  // ========== F_X (stage-2 col weights, mu from gX), 16 m-groups of 4 ==========
  if (t<64){
    float mu = gX + sub + d*(float)t;
    float astar = fminf(255.f, fmaxf(0.f, rintf(mu)));
    float t0 = (astar-mu)*(astar-mu);
    float r  = sqrtf(t0 + w88v);
    int lo = (int)ceilf(mu-r); int hi = (int)floorf(mu+r)+1;
    lo = lo<0?0:lo; hi = hi>256?256:hi; if (hi<lo) hi=lo;
    s_lo[t]=lo; s_hi[t]=hi;
  }
  __syncthreads();
  if (t<16){
    int lo=256, hi=0;
    #pragma unroll
    for (int k2=0;k2<4;++k2){ lo=min(lo,s_lo[t*4+k2]); hi=max(hi,s_hi[t*4+k2]); }
    if (hi<lo){lo=0;hi=0;}
    int lo4 = lo & ~3;                      // granule-aligned pack origin
    meta[32+t]=lo4; meta[48+t]=hi; s_glo[t]=lo4; s_ghi[t]=hi;
  }
  {
    float sum2=0.f;
    #pragma unroll
    for (int k=0;k<16;++k){
      int idx = t + 1024*k;
      int m=idx>>8, b=idx&255;
      float mu = gX + sub + d*(float)m;
      float dx=(float)b-mu;
      float e=expf(-dx*dx*inv2v);
      F[idx]=e; sum2+=e;
    }
    red[t]=sum2;
  }
  __syncthreads();
  for (int o=512;o>0;o>>=1){ if (t<o) red[t]+=red[t+o]; __syncthreads(); }
  const float scX = 1.f/red[0];
  __syncthreads();
  #pragma unroll
  for (int k=0;k<16;++k){
    int idx = t + 1024*k;
    int m=idx>>8, b=idx&255, q=m>>2;
    int lo4=s_glo[q], hi=s_ghi[q];
    if (b>=lo4 && b<hi) fxg[(size_t)((q<<10) + ((b-lo4)<<2) + (m&3))] = F[idx]*scX;
  }
}

// 4096 blocks: 4 blocks per image (16 filters each). 4 waves; wave w owns
// stage-1 n-group g=qq*4+w (4 n's) and stage-2 m-group q=w*4+(lane>>4).
__global__ __launch_bounds__(256, 8) void k_main(
    const float* __restrict__ x, const float* __restrict__ xh,
    const int* __restrict__ meta, const float* __restrict__ fyg,
    const float* __restrict__ fxg, float* __restrict__ out)
{
  __shared__ float Tt[16*256];   // swizzled T[n_local][b], 16 KiB
  const int bid = blockIdx.x;
  const int lg  = ((bid&7)<<9) | (bid>>3);   // same-image quads -> same XCD
  const int img = lg>>2, qq = lg&3;
  const int tid = threadIdx.x;
  const int w    = __builtin_amdgcn_readfirstlane(tid>>6);
  const int lane = tid & 63;
  const float* __restrict__ src = (img<NBATCH) ? (x  + (size_t)img*IMG_SZ)
                                               : (xh + (size_t)(img-NBATCH)*IMG_SZ);
  float* __restrict__ dst = ((img<NBATCH) ? (out + (size_t)img*8192)
                                          : (out + (size_t)(img-NBATCH)*8192 + 4096))
                            + qq*1024;

  // ---- stage 1: T[n][b] = sum_a FY[n][a]*src[a][b]; lane owns cols 4L..4L+3 ----
  {
    const int g  = qq*4 + w;
    const int a0 = __builtin_amdgcn_readfirstlane(meta[g]);
    const int nr = __builtin_amdgcn_readfirstlane(meta[16+g]) - a0;
    const int C  = (nr + 7) >> 3;            // 8-row chunks (zero-padded weights)
    const float* rp0 = src + 4*lane;
    const float* wp  = fyg + ((size_t)g<<10);   // [256][4], zero beyond band
    float acc[4][4];
    #pragma unroll
    for (int k2=0;k2<4;++k2){acc[k2][0]=0.f;acc[k2][1]=0.f;acc[k2][2]=0.f;acc[k2][3]=0.f;}
    for (int c=0; c<C; ++c){
      float4 A[8];                            // 8 independent loads in flight
      #pragma unroll
      for (int j=0;j<8;++j){
        int ra = a0 + c*8 + j; ra = ra>255?255:ra;   // clamped: always a valid row
        A[j] = *(const float4* __restrict__)(rp0 + (ra<<8));
      }
      #pragma unroll
      for (int j=0;j<8;++j){
        int rw = c*8 + j; rw = rw>255?255:rw;        // zero weights beyond band
        const float* wr = wp + (rw<<2);              // uniform -> s_load_dwordx4
        const float w0=wr[0], w1=wr[1], w2=wr[2], w3=wr[3];
        acc[0][0]=fmaf(w0,A[j].x,acc[0][0]); acc[0][1]=fmaf(w0,A[j].y,acc[0][1]);
        acc[0][2]=fmaf(w0,A[j].z,acc[0][2]); acc[0][3]=fmaf(w0,A[j].w,acc[0][3]);
        acc[1][0]=fmaf(w1,A[j].x,acc[1][0]); acc[1][1]=fmaf(w1,A[j].y,acc[1][1]);
        acc[1][2]=fmaf(w1,A[j].z,acc[1][2]); acc[1][3]=fmaf(w1,A[j].w,acc[1][3]);
        acc[2][0]=fmaf(w2,A[j].x,acc[2][0]); acc[2][1]=fmaf(w2,A[j].y,acc[2][1]);
        acc[2][2]=fmaf(w2,A[j].z,acc[2][2]); acc[2][3]=fmaf(w2,A[j].w,acc[2][3]);
        acc[3][0]=fmaf(w3,A[j].x,acc[3][0]); acc[3][1]=fmaf(w3,A[j].y,acc[3][1]);
        acc[3][2]=fmaf(w3,A[j].z,acc[3][2]); acc[3][3]=fmaf(w3,A[j].w,acc[3][3]);
      }
    }
    // b128 writes, granule-XOR swizzle: phys_granule = lane ^ n -> conflict-free
    #pragma unroll
    for (int k2=0;k2<4;++k2){
      const int n = w*4 + k2;                  // wave-uniform row (0..15)
      float4 v; v.x=acc[k2][0]; v.y=acc[k2][1]; v.z=acc[k2][2]; v.w=acc[k2][3];
      *(float4*)&Tt[(n<<8) + ((lane ^ n)<<2)] = v;
    }
  }
  __syncthreads();

  // ---- stage 2: out[n][m] = sum_b T[n][b]*FX[m][b]; lane = cc*16 + nl ----
  const int nl = lane & 15;
  const int cc = lane >> 4;
  const int q  = w*4 + cc;                     // one m-group of 4 per (wave,cc)
  const int lo4 = meta[32+q];
  const int hi  = meta[48+q];
  const int ng  = (hi - lo4 + 3) >> 2;
  const int u0  = lo4 >> 2;
  const float* wq = fxg + ((size_t)q<<10);     // [256][4] rows packed from lo4
  float o0=0.f,o1=0.f,o2=0.f,o3=0.f;
  #pragma unroll 2
  for (int it=0; it<ng; ++it){
    const int u = u0 + it;
    const float4 tv = *(const float4*)&Tt[(nl<<8) + ((u ^ nl)<<2)];
    const float4 w0 = *(const float4*)(wq + it*16);      // b+0: m 0..3
    const float4 w1 = *(const float4*)(wq + it*16 + 4);  // b+1
    const float4 w2 = *(const float4*)(wq + it*16 + 8);  // b+2
    const float4 w3 = *(const float4*)(wq + it*16 + 12); // b+3
    o0=fmaf(tv.x,w0.x,fmaf(tv.y,w1.x,fmaf(tv.z,w2.x,fmaf(tv.w,w3.x,o0))));
    o1=fmaf(tv.x,w0.y,fmaf(tv.y,w1.y,fmaf(tv.z,w2.y,fmaf(tv.w,w3.y,o1))));
    o2=fmaf(tv.x,w0.z,fmaf(tv.y,w1.z,fmaf(tv.z,w2.z,fmaf(tv.w,w3.z,o2))));
    o3=fmaf(tv.x,w0.w,fmaf(tv.y,w1.w,fmaf(tv.z,w2.w,fmaf(tv.w,w3.w,o3))));
  }
  __syncthreads();   // all stage-2 reads of Tt done before overwrite

  // ---- transpose via LDS (stride 68 keeps float4 16B-aligned), coalesced store ----
  {
    const int m0 = q*4;
    Tt[nl*68 + m0 + 0] = o0; Tt[nl*68 + m0 + 1] = o1;
    Tt[nl*68 + m0 + 2] = o2; Tt[nl*68 + m0 + 3] = o3;
  }
  __syncthreads();
  {
    const int f = tid*4;
    const int n = f>>6, m = f&63;
    const float4 v = *(const float4*)&Tt[n*68+m];
    *(float4*)(dst+f) = v;
  }
}

extern "C" void kernel_launch(void* const* d_in, const int* in_sizes, int n_in,
                              void* d_out, int out_size, void* d_ws, size_t ws_size,
                              hipStream_t stream)
{
  const float* x  = (const float*)d_in[0];
  const float* xh = (const float*)d_in[1];
  const float* h  = (const float*)d_in[2];   // only row 0 is used
  const float* Ww = (const float*)d_in[3];
  const float* Wb = (const float*)d_in[4];
  float* out = (float*)d_out;

  int*   meta = (int*)d_ws;
  float* fyg  = (float*)((char*)d_ws + 256);
  float* fxg  = (float*)((char*)d_ws + 256 + 65536);

  k_prep<<<1, 1024, 0, stream>>>(h, Ww, Wb, meta, fyg, fxg);
  k_main<<<8*NBATCH, 256, 0, stream>>>(x, xh, meta, fyg, fxg, out);
}

// Round 4
// 96.625 us; speedup vs baseline: 1.5508x; 1.0377x over previous
//
#include <hip/hip_runtime.h>
#include <math.h>

#define N_FILT 64
#define IMG_DIM 256
#define IMG_SZ (256*256)
#define HDIM 1024
#define NBATCH 512

// ws layout (131,328 B total):
//   int meta[64]: [0..15]=aloY [16..31]=ahiY   (16 n-groups of 4, stage 1)
//                 [32..47]=lo4X (granule-aligned) [48..63]=hiX (16 m-groups of 4)
//   byte 256           : fyg [16][256][4] float (gamma/SY folded, zero-filled) 64 KiB
//   byte 256+65536     : fxg [16][256][4] float (1/SX folded, zero-filled)     64 KiB

// grid = 2: block 0 builds the Y side (fyg, stage-1 weights, mu from par[1]),
//           block 1 builds the X side (fxg, stage-2 weights, mu from par[0]).
__global__ __launch_bounds__(256) void k_prep(
    const float* __restrict__ h, const float* __restrict__ Ww,
    const float* __restrict__ Wb, int* __restrict__ meta,
    float* __restrict__ fyg, float* __restrict__ fxg)
{
  __shared__ float partial[32];      // [wave][slot]
  __shared__ float par_s[8];
  __shared__ float F[N_FILT*IMG_DIM];
  __shared__ int s_lo[64], s_hi[64], s_glo[16], s_ghi[16];
  __shared__ float ssum[4];
  const int t   = threadIdx.x;
  const int side= blockIdx.x;        // 0=Y, 1=X
  const int wv  = t>>6, ln = t&63;
  float* __restrict__ wout = side ? fxg : fyg;

  // zero-fill this side's weight buffer (packs only overwrite in-band rows)
  {
    float4 z = make_float4(0.f,0.f,0.f,0.f);
    float4* p = (float4*)wout;
    #pragma unroll
    for (int k=0;k<16;++k) p[t + 256*k] = z;
  }

  // ---- params[j] = h[0] . W_read_w[j] + W_read_b[j] (single pass over h) ----
  {
    float s0=0.f,s1=0.f,s2=0.f,s3=0.f,s4=0.f;
    for (int k=t;k<HDIM;k+=256){
      const float hv=h[k];
      s0=fmaf(hv,Ww[k        ],s0);
      s1=fmaf(hv,Ww[HDIM+k   ],s1);
      s2=fmaf(hv,Ww[2*HDIM+k ],s2);
      s3=fmaf(hv,Ww[3*HDIM+k ],s3);
      s4=fmaf(hv,Ww[4*HDIM+k ],s4);
    }
    #pragma unroll
    for (int o=32;o>0;o>>=1){
      s0+=__shfl_down(s0,o); s1+=__shfl_down(s1,o); s2+=__shfl_down(s2,o);
      s3+=__shfl_down(s3,o); s4+=__shfl_down(s4,o);
    }
    if (ln==0){ partial[wv*8+0]=s0; partial[wv*8+1]=s1; partial[wv*8+2]=s2;
                partial[wv*8+3]=s3; partial[wv*8+4]=s4; }
  }
  __syncthreads();
  if (t<5) par_s[t]=partial[t]+partial[8+t]+partial[16+t]+partial[24+t]+Wb[t];
  __syncthreads();

  const float var   = expf(par_s[2]+1e-8f);
  const float dt    = expf(par_s[3]);
  const float gamma = expf(par_s[4]);
  const float gC = 0.5f*257.f*(par_s[side?0:1]+1.f);  // Y<-par[1], X<-par[0]
  const float d  = dt*(255.f/63.f);
  const float sub= -32.5f*d;
  const float inv2v = 1.f/(2.f*var);
  const float w88v  = 88.f*var;   // band cutoff: e(a)/e(peak) >= exp(-44)

  if (t<64){
    float mu = gC + sub + d*(float)t;
    float astar = fminf(255.f, fmaxf(0.f, rintf(mu)));   // clamped peak
    float t0 = (astar-mu)*(astar-mu);
    float r  = sqrtf(t0 + w88v);
    int lo = (int)ceilf(mu-r); int hi = (int)floorf(mu+r)+1;
    lo = lo<0?0:lo; hi = hi>256?256:hi; if (hi<lo) hi=lo;
    s_lo[t]=lo; s_hi[t]=hi;
  }
  __syncthreads();
  if (t<16){
    int lo=256, hi=0;
    #pragma unroll
    for (int k2=0;k2<4;++k2){ lo=min(lo,s_lo[t*4+k2]); hi=max(hi,s_hi[t*4+k2]); }
    if (hi<lo){lo=0;hi=0;}
    if (side==0){ meta[t]=lo; meta[16+t]=hi; }
    else        { lo &= ~3;  meta[32+t]=lo; meta[48+t]=hi; }  // granule-aligned
    s_glo[t]=lo; s_ghi[t]=hi;
  }
  // F + global sum
  float sum=0.f;
  #pragma unroll
  for (int k=0;k<64;++k){
    int idx=t+256*k;
    int n=idx>>8, a=idx&255;
    float mu = gC+sub+d*(float)n;
    float dx=(float)a-mu;
    float e=expf(-dx*dx*inv2v);
    F[idx]=e; sum+=e;
  }
  #pragma unroll
  for (int o=32;o>0;o>>=1) sum+=__shfl_down(sum,o);
  if (ln==0) ssum[wv]=sum;
  __syncthreads();
  const float stot = ssum[0]+ssum[1]+ssum[2]+ssum[3];
  const float sc = (side==0 ? gamma : 1.f)/stot;   // fold gamma into Y side
  #pragma unroll
  for (int k=0;k<64;++k){
    int idx=t+256*k;
    int n=idx>>8, a=idx&255, g=n>>2;
    int lo=s_glo[g], hi=s_ghi[g];
    if (a>=lo && a<hi) wout[(size_t)((g<<10)+((a-lo)<<2)+(n&3))] = F[idx]*sc;
  }
}

// 4096 blocks: 4 blocks per image (16 filters each). 4 waves; wave w owns
// stage-1 n-group g=qq*4+w (4 n's) and stage-2 m-group q=w*4+(lane>>4).
__global__ __launch_bounds__(256, 5) void k_main(
    const float* __restrict__ x, const float* __restrict__ xh,
    const int* __restrict__ meta, const float* __restrict__ fyg,
    const float* __restrict__ fxg, float* __restrict__ out)
{
  __shared__ float Tt[16*256];   // swizzled T[n_local][b], 16 KiB
  const int bid = blockIdx.x;
  const int lg  = ((bid&7)<<9) | (bid>>3);   // same-image quads -> same XCD
  const int img = lg>>2, qq = lg&3;
  const int tid = threadIdx.x;
  const int w    = __builtin_amdgcn_readfirstlane(tid>>6);
  const int lane = tid & 63;
  const float* __restrict__ src = (img<NBATCH) ? (x  + (size_t)img*IMG_SZ)
                                               : (xh + (size_t)(img-NBATCH)*IMG_SZ);
  float* __restrict__ dst = ((img<NBATCH) ? (out + (size_t)img*8192)
                                          : (out + (size_t)(img-NBATCH)*8192 + 4096))
                            + qq*1024;

  // ---- stage 1: T[n][b] = sum_a FY[n][a]*src[a][b]; lane owns cols 4L..4L+3 ----
  {
    const int g  = qq*4 + w;
    const int a0 = __builtin_amdgcn_readfirstlane(meta[g]);
    const int nr = __builtin_amdgcn_readfirstlane(meta[16+g]) - a0;
    const int C  = (nr + 7) >> 3;            // 8-row chunks (zero-padded weights)
    const float* rp0 = src + 4*lane;
    const float* wp  = fyg + ((size_t)g<<10);   // [256][4], zero beyond band
    float acc[4][4];
    #pragma unroll
    for (int k2=0;k2<4;++k2){acc[k2][0]=0.f;acc[k2][1]=0.f;acc[k2][2]=0.f;acc[k2][3]=0.f;}
    #pragma unroll 1
    for (int c=0; c<C; ++c){
      // -------- batch: 8 global loads + 8 uniform weight loads, all in flight
      float4 A[8];
      float wt0[8], wt1[8], wt2[8], wt3[8];
      #pragma unroll
      for (int j=0;j<8;++j){
        int ra = a0 + c*8 + j; ra = ra>255?255:ra;   // clamped: valid row
        A[j] = *(const float4* __restrict__)(rp0 + (ra<<8));
        int rw = c*8 + j; rw = rw>255?255:rw;        // zero weights beyond band
        const float* wr = wp + (rw<<2);              // uniform -> s_load
        wt0[j]=wr[0]; wt1[j]=wr[1]; wt2[j]=wr[2]; wt3[j]=wr[3];
      }
      __builtin_amdgcn_sched_barrier(0);             // keep loads batched ahead
      #pragma unroll
      for (int j=0;j<8;++j){
        acc[0][0]=fmaf(wt0[j],A[j].x,acc[0][0]); acc[0][1]=fmaf(wt0[j],A[j].y,acc[0][1]);
        acc[0][2]=fmaf(wt0[j],A[j].z,acc[0][2]); acc[0][3]=fmaf(wt0[j],A[j].w,acc[0][3]);
        acc[1][0]=fmaf(wt1[j],A[j].x,acc[1][0]); acc[1][1]=fmaf(wt1[j],A[j].y,acc[1][1]);
        acc[1][2]=fmaf(wt1[j],A[j].z,acc[1][2]); acc[1][3]=fmaf(wt1[j],A[j].w,acc[1][3]);
        acc[2][0]=fmaf(wt2[j],A[j].x,acc[2][0]); acc[2][1]=fmaf(wt2[j],A[j].y,acc[2][1]);
        acc[2][2]=fmaf(wt2[j],A[j].z,acc[2][2]); acc[2][3]=fmaf(wt2[j],A[j].w,acc[2][3]);
        acc[3][0]=fmaf(wt3[j],A[j].x,acc[3][0]); acc[3][1]=fmaf(wt3[j],A[j].y,acc[3][1]);
        acc[3][2]=fmaf(wt3[j],A[j].z,acc[3][2]); acc[3][3]=fmaf(wt3[j],A[j].w,acc[3][3]);
      }
      __builtin_amdgcn_sched_barrier(0);
    }
    // b128 writes, granule-XOR swizzle: phys_granule = lane ^ n -> conflict-free
    #pragma unroll
    for (int k2=0;k2<4;++k2){
      const int n = w*4 + k2;                  // wave-uniform row (0..15)
      float4 v; v.x=acc[k2][0]; v.y=acc[k2][1]; v.z=acc[k2][2]; v.w=acc[k2][3];
      *(float4*)&Tt[(n<<8) + ((lane ^ n)<<2)] = v;
    }
  }
  __syncthreads();

  // ---- stage 2: out[n][m] = sum_b T[n][b]*FX[m][b]; lane = cc*16 + nl ----
  const int nl = lane & 15;
  const int cc = lane >> 4;
  const int q  = w*4 + cc;                     // one m-group of 4 per (wave,cc)
  const int lo4 = meta[32+q];
  const int hi  = meta[48+q];
  int ngu = (hi - lo4 + 3) >> 2;
  ngu = max(ngu, __shfl_xor(ngu,16));          // wave-uniform trip count
  ngu = max(ngu, __shfl_xor(ngu,32));          // (overrun iters: zero weights)
  const int u0  = lo4 >> 2;
  const float* wq = fxg + ((size_t)q<<10);     // [256][4] rows packed from lo4
  float o0=0.f,o1=0.f,o2=0.f,o3=0.f;
  #pragma unroll 1
  for (int it=0; it<ngu; it+=2){
    // batch the 10 loads of two granule-iterations, then fence, then FMA
    const int uA = min(u0+it,   63);
    const int uB = min(u0+it+1, 63);
    const float4 tvA = *(const float4*)&Tt[(nl<<8) + ((uA ^ nl)<<2)];
    const float4 tvB = *(const float4*)&Tt[(nl<<8) + ((uB ^ nl)<<2)];
    const float4 a0w = *(const float4*)(wq + it*16);
    const float4 a1w = *(const float4*)(wq + it*16 + 4);
    const float4 a2w = *(const float4*)(wq + it*16 + 8);
    const float4 a3w = *(const float4*)(wq + it*16 + 12);
    const float4 b0w = *(const float4*)(wq + it*16 + 16);
    const float4 b1w = *(const float4*)(wq + it*16 + 20);
    const float4 b2w = *(const float4*)(wq + it*16 + 24);
    const float4 b3w = *(const float4*)(wq + it*16 + 28);
    __builtin_amdgcn_sched_barrier(0);
    o0=fmaf(tvA.x,a0w.x,fmaf(tvA.y,a1w.x,fmaf(tvA.z,a2w.x,fmaf(tvA.w,a3w.x,o0))));
    o1=fmaf(tvA.x,a0w.y,fmaf(tvA.y,a1w.y,fmaf(tvA.z,a2w.y,fmaf(tvA.w,a3w.y,o1))));
    o2=fmaf(tvA.x,a0w.z,fmaf(tvA.y,a1w.z,fmaf(tvA.z,a2w.z,fmaf(tvA.w,a3w.z,o2))));
    o3=fmaf(tvA.x,a0w.w,fmaf(tvA.y,a1w.w,fmaf(tvA.z,a2w.w,fmaf(tvA.w,a3w.w,o3))));
    if (it+1 < ngu){
      o0=fmaf(tvB.x,b0w.x,fmaf(tvB.y,b1w.x,fmaf(tvB.z,b2w.x,fmaf(tvB.w,b3w.x,o0))));
      o1=fmaf(tvB.x,b0w.y,fmaf(tvB.y,b1w.y,fmaf(tvB.z,b2w.y,fmaf(tvB.w,b3w.y,o1))));
      o2=fmaf(tvB.x,b0w.z,fmaf(tvB.y,b1w.z,fmaf(tvB.z,b2w.z,fmaf(tvB.w,b3w.z,o2))));
      o3=fmaf(tvB.x,b0w.w,fmaf(tvB.y,b1w.w,fmaf(tvB.z,b2w.w,fmaf(tvB.w,b3w.w,o3))));
    }
    __builtin_amdgcn_sched_barrier(0);
  }
  __syncthreads();   // all stage-2 reads of Tt done before overwrite

  // ---- transpose via LDS (stride 68 keeps float4 16B-aligned), coalesced store ----
  {
    const int m0 = q*4;
    Tt[nl*68 + m0 + 0] = o0; Tt[nl*68 + m0 + 1] = o1;
    Tt[nl*68 + m0 + 2] = o2; Tt[nl*68 + m0 + 3] = o3;
  }
  __syncthreads();
  {
    const int f = tid*4;
    const int n = f>>6, m = f&63;
    const float4 v = *(const float4*)&Tt[n*68+m];
    *(float4*)(dst+f) = v;
  }
}

extern "C" void kernel_launch(void* const* d_in, const int* in_sizes, int n_in,
                              void* d_out, int out_size, void* d_ws, size_t ws_size,
                              hipStream_t stream)
{
  const float* x  = (const float*)d_in[0];
  const float* xh = (const float*)d_in[1];
  const float* h  = (const float*)d_in[2];   // only row 0 is used
  const float* Ww = (const float*)d_in[3];
  const float* Wb = (const float*)d_in[4];
  float* out = (float*)d_out;

  int*   meta = (int*)d_ws;
  float* fyg  = (float*)((char*)d_ws + 256);
  float* fxg  = (float*)((char*)d_ws + 256 + 65536);

  k_prep<<<2, 256, 0, stream>>>(h, Ww, Wb, meta, fyg, fxg);
  k_main<<<8*NBATCH, 256, 0, stream>>>(x, xh, meta, fyg, fxg, out);
}